// Round 20
// baseline (258.875 us; speedup 1.0000x reference)
//
#include <hip/hip_runtime.h>
#include <stdint.h>

typedef unsigned short u16;
typedef __attribute__((ext_vector_type(8))) short s16x8;   // 8 bf16 in 4 VGPRs
typedef __attribute__((ext_vector_type(4))) float f32x4;   // MFMA accumulator
typedef __attribute__((ext_vector_type(4))) unsigned uint4v;

#define NEXP 8
#define HD 1024
#define DFF 4096
#define BM 128
#define BN 128
#define BK 64     // 128B rows; XOR-swizzled LDS (T21 both-sides)

#define TILE_U16 (BM * BK)   // 8192 u16 = 16KB per GEMM LDS tile

__device__ __forceinline__ u16 f2bf(float f) {
  union { float f; unsigned u; } c; c.f = f;
  unsigned r = c.u + 0x7fffu + ((c.u >> 16) & 1u);   // RNE
  return (u16)(r >> 16);
}

__device__ __forceinline__ unsigned cvtpk(float a, float b) {
  unsigned r;
  asm("v_cvt_pk_bf16_f32 %0, %1, %2" : "=v"(r) : "v"(a), "v"(b));
  return r;   // lo = bf16(a), hi = bf16(b)
}

__device__ __forceinline__ void gload_lds16(const void* g, const void* l) {
  __builtin_amdgcn_global_load_lds(
      (const __attribute__((address_space(1))) unsigned int*)(uintptr_t)g,
      (__attribute__((address_space(3))) unsigned int*)(unsigned)(uintptr_t)l,
      16, 0, 0);
}

// Persistent 4-tile transpose+convert into k-panel layout, double-buffered LDS.
// W f32 [K][N] -> Wp bf16 [K/64][N][64].  Tile = 128k x 64n staged via gload_lds
// into Tf[buf][128][64]; STAGE(next tile) issued BEFORE PHASE2(current) so HBM
// latency hides under the ~700cy LDS-read/cvt/store phase; one barrier per tile.
template <int K, int N>
__device__ __forceinline__ void convt_quad_gl(const float* __restrict__ W,
    u16* __restrict__ Wp, int b0, float* __restrict__ Tf0, float* __restrict__ Tf1) {
  const int t = threadIdx.x;
  constexpr int TPE = (K / 128) * (N / 64);   // 512 tiles/expert
  const float* sp[4];
  u16* dp[4];
#pragma unroll
  for (int i = 0; i < 4; ++i) {
    int idx = b0 + i;
    int e = idx / TPE, ti = idx % TPE;
    int k0 = (ti % (K / 128)) * 128, n0 = (ti / (K / 128)) * 64;
    sp[i] = W + (size_t)e * K * N + (size_t)k0 * N + n0;
    dp[i] = Wp + (size_t)e * K * N + (size_t)(k0 / 64) * N * 64 + (size_t)n0 * 64;
  }
  const int p = t >> 7, nl = (t & 127) >> 1, kh = t & 1;

#define STAGE_T(Tf, i) do { \
    _Pragma("unroll") for (int c_ = 0; c_ < 8; ++c_) { \
      int slot_ = c_ * 256 + t; \
      gload_lds16(sp[i] + (size_t)(slot_ >> 4) * N + (slot_ & 15) * 4, (Tf) + slot_ * 4); \
    } \
  } while (0)

#define PHASE2_T(Tf, i) do { \
    float v_[32]; \
    _Pragma("unroll") for (int j_ = 0; j_ < 32; ++j_) \
      v_[j_] = (Tf)[(p * 64 + kh * 32 + j_) * 64 + nl]; \
    uint4v q0_, q1_, q2_, q3_; \
    _Pragma("unroll") for (int a_ = 0; a_ < 4; ++a_) { \
      q0_[a_] = cvtpk(v_[2 * a_], v_[2 * a_ + 1]); \
      q1_[a_] = cvtpk(v_[8 + 2 * a_], v_[9 + 2 * a_]); \
      q2_[a_] = cvtpk(v_[16 + 2 * a_], v_[17 + 2 * a_]); \
      q3_[a_] = cvtpk(v_[24 + 2 * a_], v_[25 + 2 * a_]); \
    } \
    u16* d_ = dp[i] + (size_t)p * N * 64 + (size_t)nl * 64 + kh * 32; \
    *(uint4v*)d_ = q0_; \
    *(uint4v*)(d_ + 8) = q1_; \
    *(uint4v*)(d_ + 16) = q2_; \
    *(uint4v*)(d_ + 24) = q3_; \
  } while (0)

  STAGE_T(Tf0, 0);
  __syncthreads();
  STAGE_T(Tf1, 1);          // in flight under phase2(0)
  PHASE2_T(Tf0, 0);
  __syncthreads();
  STAGE_T(Tf0, 2);
  PHASE2_T(Tf1, 1);
  __syncthreads();
  STAGE_T(Tf1, 3);
  PHASE2_T(Tf0, 2);
  __syncthreads();
  PHASE2_T(Tf1, 3);

#undef STAGE_T
#undef PHASE2_T
}

// prep1: router (4 tokens/block, wave per token; emits bf16 x) + W1 convt.
__global__ __launch_bounds__(256) void prep1_k(
    const float* __restrict__ x, const float* __restrict__ Wr,
    const float* __restrict__ br,
    int* __restrict__ tok_exp, float* __restrict__ tok_gate,
    const float* __restrict__ W1, u16* __restrict__ W1t,
    u16* __restrict__ Xbf, int T) {
  __shared__ __align__(16) float Tf[2][128 * 64];   // 64KB double buffer
  const int bid = blockIdx.x;
  const int NBR = T / 4;
  if (bid >= NBR) {
    convt_quad_gl<HD, DFF>(W1, W1t, (bid - NBR) * 4, Tf[0], Tf[1]);
    return;
  }
  const int w = threadIdx.x >> 6, l = threadIdx.x & 63;
  const int t = bid * 4 + w;
  const float4* xr = (const float4*)(x + (size_t)t * HD);
  float acc[NEXP];
#pragma unroll
  for (int j = 0; j < NEXP; ++j) acc[j] = 0.f;
#pragma unroll
  for (int i = 0; i < 4; ++i) {
    float4 v = xr[l + i * 64];
    unsigned pa = cvtpk(v.x, v.y), pb = cvtpk(v.z, v.w);
    *(uint2*)&Xbf[(size_t)t * HD + (l + i * 64) * 4] = make_uint2(pa, pb);
    const int h = (l + i * 64) * 4;
    const float* w0 = Wr + (size_t)h * NEXP;
#pragma unroll
    for (int c = 0; c < 4; ++c) {
      float xv = (c == 0) ? v.x : (c == 1) ? v.y : (c == 2) ? v.z : v.w;
      const float4* wr4 = (const float4*)(w0 + c * NEXP);
      float4 a = wr4[0], b = wr4[1];
      acc[0] += xv * a.x; acc[1] += xv * a.y; acc[2] += xv * a.z; acc[3] += xv * a.w;
      acc[4] += xv * b.x; acc[5] += xv * b.y; acc[6] += xv * b.z; acc[7] += xv * b.w;
    }
  }
#pragma unroll
  for (int j = 0; j < NEXP; ++j)
#pragma unroll
    for (int off = 32; off > 0; off >>= 1) acc[j] += __shfl_xor(acc[j], off);
  if (l == 0) {
    float lg[NEXP];
    float best = acc[0] + br[0]; int bi = 0;
    lg[0] = best;
#pragma unroll
    for (int j = 1; j < NEXP; ++j) {
      lg[j] = acc[j] + br[j];
      if (lg[j] > best) { best = lg[j]; bi = j; }
    }
    float s = 0.f;
#pragma unroll
    for (int j = 0; j < NEXP; ++j) s += expf(lg[j] - best);
    tok_exp[t] = bi;
    tok_gate[t] = 1.0f / s;
  }
}

// scan: count experts from tok_exp (no atomics), prefix, tile table.
__global__ __launch_bounds__(64) void scan_k(const int* __restrict__ tok_exp, int T,
    int* __restrict__ seg, int* __restrict__ cursor,
    int* __restrict__ ntile, int* __restrict__ tile_e, int* __restrict__ tile_m) {
  const int l = threadIdx.x;
  int cnt[NEXP];
#pragma unroll
  for (int j = 0; j < NEXP; ++j) cnt[j] = 0;
  for (int i = l; i < T; i += 64) {
    int e = tok_exp[i];
#pragma unroll
    for (int j = 0; j < NEXP; ++j) cnt[j] += (e == j) ? 1 : 0;
  }
#pragma unroll
  for (int j = 0; j < NEXP; ++j)
#pragma unroll
    for (int off = 32; off > 0; off >>= 1) cnt[j] += __shfl_xor(cnt[j], off);
  if (l == 0) {
    int s = 0, nt = 0;
#pragma unroll
    for (int e = 0; e < NEXP; ++e) {
      seg[e] = s; cursor[e] = s;
      int c = cnt[e];
      for (int m = 0; m < c; m += BM) { tile_e[nt] = e; tile_m[nt] = m; ++nt; }
      s += c;
    }
    seg[NEXP] = s;
    ntile[0] = nt;
  }
}

// gather-lite: build perm/gatep only (no data copy) — 1 thread/token.
__global__ __launch_bounds__(256) void gatherlite_k(const int* __restrict__ tok_exp,
    const float* __restrict__ tok_gate, int* __restrict__ cursor,
    int* __restrict__ perm, float* __restrict__ gatep) {
  const int t = blockIdx.x * 256 + threadIdx.x;
  int e = tok_exp[t];
  int pos = atomicAdd(&cursor[e], 1);
  perm[pos] = t;
  gatep[pos] = tok_gate[t];
}

// Grouped GEMM body, BK=64, XOR-swizzled LDS, double-buffered single-barrier.
// A: AIND ? Xbf[perm[s0+row]] : A[s0+row]  ([T][KD] bf16 rows).
// B: Wp panels [KD/64][ND][64] bf16 (per-tt stride = ND*64).
// EPI 0: H1out = bf16(relu(acc+bias)).   EPI 2: Pt[ks][row][n] = acc (f32 partial).
template <int KD, int ND, int EPI, int KSPLIT, bool AIND>
__device__ __forceinline__ void gemm_body(
    u16* __restrict__ sh,   // 4 x TILE_U16: As0 | Bs0 | As1 | Bs1
    const u16* __restrict__ A, const u16* __restrict__ Bp,
    const float* __restrict__ bias, const int* __restrict__ seg,
    const int* __restrict__ ntile, const int* __restrict__ tile_e,
    const int* __restrict__ tile_m, const int* __restrict__ perm,
    u16* __restrict__ H1out, float* __restrict__ Pt,
    int bx, int by, int ks) {
  if (by >= ntile[0]) return;
  const int e  = tile_e[by];
  const int m0 = tile_m[by];
  const int s0 = seg[e];
  const int cnt = seg[e + 1] - s0;
  const int n0 = bx * BN;
  constexpr int NT = (KD / KSPLIT) / BK;
  constexpr size_t BSTEP = (size_t)ND * 64;      // one k-panel of B
  const int kbase = ks * (KD / KSPLIT);

  const int t = threadIdx.x;
  const int l = t & 63, w = t >> 6;
  const int wr = w >> 1, wc = w & 1;

  const f32x4 fzero = {0.f, 0.f, 0.f, 0.f};
  f32x4 acc[4][4];
#pragma unroll
  for (int i = 0; i < 4; ++i)
#pragma unroll
    for (int j = 0; j < 4; ++j) acc[i][j] = fzero;

  const int sub = t & 7, r8 = t >> 3;
  const int koff = (sub ^ (r8 & 7)) * 8;
  int aoff[4], boff[4];
  const u16* bte = Bp + (size_t)e * ND * KD;
#pragma unroll
  for (int c = 0; c < 4; ++c) {
    int row = c * 32 + r8;
    int rg = m0 + row; if (rg >= cnt) rg = cnt - 1;
    int arow;
    if constexpr (AIND) arow = perm[s0 + rg];   // token index
    else arow = s0 + rg;                         // positional
    aoff[c] = arow * KD + kbase + koff;
    boff[c] = (kbase / 64) * (int)BSTEP + (n0 + row) * 64 + koff;
  }

  u16* Ac = sh;
  u16* Bc = sh + TILE_U16;
  u16* An = sh + 2 * TILE_U16;
  u16* Bn = sh + 3 * TILE_U16;

#define STAGE(pa, pb, tt) do { \
    _Pragma("unroll") for (int c_ = 0; c_ < 4; ++c_) \
      gload_lds16(A + (size_t)aoff[c_] + (size_t)(tt) * BK, (pa) + (c_ * 256 + t) * 8); \
    _Pragma("unroll") for (int c_ = 0; c_ < 4; ++c_) \
      gload_lds16(bte + (size_t)boff[c_] + (size_t)(tt) * BSTEP, (pb) + (c_ * 256 + t) * 8); \
  } while (0)

#define COMPUTE(pa, pb) do { \
    _Pragma("unroll") for (int s_ = 0; s_ < 2; ++s_) { \
      const int fo_ = ((s_ * 4 + (l >> 4)) ^ (l & 7)) * 8; \
      s16x8 af_[4], bf_[4]; \
      _Pragma("unroll") for (int mi_ = 0; mi_ < 4; ++mi_) \
        af_[mi_] = *(const s16x8*)&(pa)[(wr * 64 + mi_ * 16 + (l & 15)) * BK + fo_]; \
      _Pragma("unroll") for (int ni_ = 0; ni_ < 4; ++ni_) \
        bf_[ni_] = *(const s16x8*)&(pb)[(wc * 64 + ni_ * 16 + (l & 15)) * BK + fo_]; \
      _Pragma("unroll") for (int mi_ = 0; mi_ < 4; ++mi_) \
        _Pragma("unroll") for (int ni_ = 0; ni_ < 4; ++ni_) \
          acc[mi_][ni_] = __builtin_amdgcn_mfma_f32_16x16x32_bf16(af_[mi_], bf_[ni_], acc[mi_][ni_], 0, 0, 0); \
    } \
  } while (0)

  STAGE(Ac, Bc, 0);
  __syncthreads();
  for (int tt = 0; tt < NT; ++tt) {
    if (tt + 1 < NT) STAGE(An, Bn, tt + 1);   // hides under COMPUTE below
    COMPUTE(Ac, Bc);
    if (tt + 1 < NT) {
      __syncthreads();                         // next stage landed; cur reads done
      u16* xp;
      xp = Ac; Ac = An; An = xp;
      xp = Bc; Bc = Bn; Bn = xp;
    }
  }

#undef STAGE
#undef COMPUTE

  const int lr = (l >> 4) * 4;
  const int lc = l & 15;

  if constexpr (EPI == 0) {
    float bv2[4];
#pragma unroll
    for (int ni = 0; ni < 4; ++ni)
      bv2[ni] = bias[(size_t)e * ND + n0 + wc * 64 + ni * 16 + lc];
#pragma unroll
    for (int mi = 0; mi < 4; ++mi) {
#pragma unroll
      for (int r = 0; r < 4; ++r) {
        int row = m0 + wr * 64 + mi * 16 + lr + r;
        if (row < cnt) {
          u16* hrow = H1out + (size_t)(s0 + row) * ND + n0 + wc * 64;
#pragma unroll
          for (int ni = 0; ni < 4; ++ni) {
            float v = acc[mi][ni][r] + bv2[ni];
            v = v > 0.f ? v : 0.f;
            hrow[ni * 16 + lc] = f2bf(v);
          }
        }
      }
    }
  } else {
    const int totT = seg[NEXP];
#pragma unroll
    for (int mi = 0; mi < 4; ++mi) {
#pragma unroll
      for (int r = 0; r < 4; ++r) {
        int row = m0 + wr * 64 + mi * 16 + lr + r;
        if (row < cnt) {
          float* prow = Pt + ((size_t)ks * totT + s0 + row) * ND + n0 + wc * 64;
#pragma unroll
          for (int ni = 0; ni < 4; ++ni)
            prow[ni * 16 + lc] = acc[mi][ni][r];
        }
      }
    }
  }
}

// Fused: GEMM1 blocks first, then W2-convt blocks (pipelined quad).
// W2t is only read by the NEXT launch (gemm2) -> completion guaranteed.
__global__ __launch_bounds__(256, 2) void gemm1_fused_k(
    const u16* __restrict__ Xbf, const u16* __restrict__ W1t,
    const float* __restrict__ b1, const int* __restrict__ seg,
    const int* __restrict__ ntile, const int* __restrict__ tile_e,
    const int* __restrict__ tile_m, const int* __restrict__ perm,
    u16* __restrict__ H1,
    const float* __restrict__ W2, u16* __restrict__ W2t, int ng1) {
  __shared__ __align__(16) u16 sh[4 * TILE_U16];   // 64KB; convt uses as 2 f32 bufs
  const int bid = blockIdx.x;
  if (bid < ng1) {
    gemm_body<HD, DFF, 0, 1, true>(sh, Xbf, W1t, b1, seg, ntile, tile_e, tile_m,
                                   perm, H1, nullptr,
                                   bid % (DFF / BN), bid / (DFF / BN), 0);
  } else {
    convt_quad_gl<DFF, HD>(W2, W2t, (bid - ng1) * 4,
                           (float*)sh, (float*)(sh + 2 * TILE_U16));
  }
}

__global__ __launch_bounds__(256, 2) void gemm2_k(
    const u16* __restrict__ H1, const u16* __restrict__ W2t,
    const int* __restrict__ seg, const int* __restrict__ ntile,
    const int* __restrict__ tile_e, const int* __restrict__ tile_m,
    float* __restrict__ Pt) {
  __shared__ __align__(16) u16 sh[4 * TILE_U16];
  gemm_body<DFF, HD, 2, 2, false>(sh, H1, W2t, nullptr, seg, ntile, tile_e,
                                  tile_m, nullptr, nullptr, Pt,
                                  blockIdx.x, blockIdx.y, blockIdx.z);
}

// out[perm[pos]] = gate[pos] * (b2[e] + sum_ks Pt[ks][pos][:])   (KSPLIT=2)
__global__ __launch_bounds__(256) void reduce_k(const float* __restrict__ Pt,
    const float* __restrict__ b2, const int* __restrict__ perm,
    const float* __restrict__ gatep, const int* __restrict__ tok_exp,
    float* __restrict__ out) {
  const int pos = blockIdx.x;
  const int totT = gridDim.x;
  const int tok = perm[pos];
  const float g = gatep[pos];
  const int e = tok_exp[tok];
  const int h = threadIdx.x * 4;
  float4 s = *(const float4*)(Pt + ((size_t)0 * totT + pos) * HD + h);
  float4 p = *(const float4*)(Pt + ((size_t)1 * totT + pos) * HD + h);
  s.x += p.x; s.y += p.y; s.z += p.z; s.w += p.w;
  float4 b = *(const float4*)(b2 + (size_t)e * HD + h);
  float4 o;
  o.x = (s.x + b.x) * g; o.y = (s.y + b.y) * g;
  o.z = (s.z + b.z) * g; o.w = (s.w + b.w) * g;
  *(float4*)(out + (size_t)tok * HD + h) = o;
}

extern "C" void kernel_launch(void* const* d_in, const int* in_sizes, int n_in,
                              void* d_out, int out_size, void* d_ws, size_t ws_size,
                              hipStream_t stream) {
  const float* x  = (const float*)d_in[0];
  const float* Wr = (const float*)d_in[1];
  const float* br = (const float*)d_in[2];
  const float* W1 = (const float*)d_in[3];
  const float* b1 = (const float*)d_in[4];
  const float* W2 = (const float*)d_in[5];
  const float* b2 = (const float*)d_in[6];
  float* out = (float*)d_out;

  const int T = in_sizes[0] / HD;   // 4096 tokens
  char* ws = (char*)d_ws;
  int*   cursor   = (int*)(ws + 64);
  int*   seg      = (int*)(ws + 128);
  int*   ntile    = (int*)(ws + 192);
  int*   tile_e   = (int*)(ws + 256);
  int*   tile_m   = (int*)(ws + 512);
  int*   tok_exp  = (int*)(ws + 1024);
  float* tok_gate = (float*)(ws + 1024 + 4 * (size_t)T);
  int*   perm     = (int*)(ws + 1024 + 8 * (size_t)T);
  float* gatep    = (float*)(ws + 1024 + 12 * (size_t)T);
  u16*   Xbf      = (u16*)(ws + 1024 + 16 * (size_t)T);                       // T*HD bf16 (8MB), token order
  u16*   H1       = (u16*)(ws + 1024 + 16 * (size_t)T + 2 * (size_t)T * HD);  // T*DFF bf16 (32MB)
  size_t off2     = 1024 + 16 * (size_t)T + 2 * (size_t)T * HD + 2 * (size_t)T * DFF;
  u16*   W1t      = (u16*)(ws + off2);                                        // panel layout (64MB)
  u16*   W2t      = (u16*)(ws + off2 + 2 * (size_t)NEXP * HD * DFF);          // panel layout (64MB)
  float* Pt       = (float*)W1t;   // GEMM2 split-K partials (2*T*HD f32 = 32MB) reuse W1t

  const int NBR = T / 4;
  const int NCB = 512 * NEXP / 4;   // 1024 convt blocks per weight (4 tiles each)
  hipLaunchKernelGGL(prep1_k, dim3(NBR + NCB), dim3(256), 0, stream,
                     x, Wr, br, tok_exp, tok_gate, W1, W1t, Xbf, T);
  hipLaunchKernelGGL(scan_k, dim3(1), dim3(64), 0, stream,
                     tok_exp, T, seg, cursor, ntile, tile_e, tile_m);
  hipLaunchKernelGGL(gatherlite_k, dim3(T / 256), dim3(256), 0, stream,
                     tok_exp, tok_gate, cursor, perm, gatep);
  const int maxtile = (T + BM - 1) / BM + NEXP - 1;   // 39 worst case
  const int ng1 = (DFF / BN) * maxtile;               // 1248 GEMM1 blocks
  hipLaunchKernelGGL(gemm1_fused_k, dim3(ng1 + NCB), dim3(256), 0, stream,
                     Xbf, W1t, b1, seg, ntile, tile_e, tile_m, perm, H1, W2, W2t, ng1);
  hipLaunchKernelGGL(gemm2_k, dim3(HD / BN, maxtile, 2), dim3(256), 0, stream,
                     H1, W2t, seg, ntile, tile_e, tile_m, Pt);
  hipLaunchKernelGGL(reduce_k, dim3(T), dim3(256), 0, stream, Pt, b2, perm, gatep, tok_exp, out);
}

// Round 21
// 258.091 us; speedup vs baseline: 1.0030x; 1.0030x over previous
//
#include <hip/hip_runtime.h>
#include <stdint.h>

typedef unsigned short u16;
typedef __attribute__((ext_vector_type(8))) short s16x8;   // 8 bf16 in 4 VGPRs
typedef __attribute__((ext_vector_type(4))) float f32x4;   // MFMA accumulator
typedef __attribute__((ext_vector_type(4))) unsigned uint4v;

#define NEXP 8
#define HD 1024
#define DFF 4096
#define BM 128
#define BN 128
#define BK 64     // 128B rows; XOR-swizzled LDS (T21 both-sides)

#define TILE_U16 (BM * BK)   // 8192 u16 = 16KB per GEMM LDS tile

__device__ __forceinline__ u16 f2bf(float f) {
  union { float f; unsigned u; } c; c.f = f;
  unsigned r = c.u + 0x7fffu + ((c.u >> 16) & 1u);   // RNE
  return (u16)(r >> 16);
}

__device__ __forceinline__ unsigned cvtpk(float a, float b) {
  unsigned r;
  asm("v_cvt_pk_bf16_f32 %0, %1, %2" : "=v"(r) : "v"(a), "v"(b));
  return r;   // lo = bf16(a), hi = bf16(b)
}

__device__ __forceinline__ void gload_lds16(const void* g, const void* l) {
  __builtin_amdgcn_global_load_lds(
      (const __attribute__((address_space(1))) unsigned int*)(uintptr_t)g,
      (__attribute__((address_space(3))) unsigned int*)(unsigned)(uintptr_t)l,
      16, 0, 0);
}

// Transpose+convert into k-panel layout (r19-proven, 32KB single buffer):
// W f32 [K][N] -> Wp bf16 [K/64][N][64].  Tile = 128k x 64n via gload_lds.
template <int K, int N>
__device__ __forceinline__ void convt_gl(const float* __restrict__ W,
    u16* __restrict__ Wp, int idx, float* __restrict__ Tf) {
  const int e = idx >> 9;                        // (K/128)*(N/64) = 512 tiles/expert
  const int ti = idx & 511;
  const int k0 = (ti % (K / 128)) * 128;
  const int n0 = (ti / (K / 128)) * 64;
  const int t = threadIdx.x;
  const float* src = W + (size_t)e * K * N + (size_t)k0 * N + n0;
#pragma unroll
  for (int c = 0; c < 8; ++c) {
    int slot = c * 256 + t;
    gload_lds16(src + (size_t)(slot >> 4) * N + (slot & 15) * 4, Tf + slot * 4);
  }
  __syncthreads();
  const int p = t >> 7, nl = (t & 127) >> 1, kh = t & 1;
  float v[32];
#pragma unroll
  for (int j = 0; j < 32; ++j)
    v[j] = Tf[(p * 64 + kh * 32 + j) * 64 + nl];
  uint4v q0, q1, q2, q3;
#pragma unroll
  for (int a = 0; a < 4; ++a) {
    q0[a] = cvtpk(v[2 * a], v[2 * a + 1]);
    q1[a] = cvtpk(v[8 + 2 * a], v[9 + 2 * a]);
    q2[a] = cvtpk(v[16 + 2 * a], v[17 + 2 * a]);
    q3[a] = cvtpk(v[24 + 2 * a], v[25 + 2 * a]);
  }
  u16* d = Wp + (size_t)e * K * N + ((size_t)(k0 / 64 + p)) * N * 64
         + (size_t)(n0 + nl) * 64 + kh * 32;
  *(uint4v*)d = q0;
  *(uint4v*)(d + 8) = q1;
  *(uint4v*)(d + 16) = q2;
  *(uint4v*)(d + 24) = q3;
}

// prep1: router (4 tokens/block, wave per token; emits bf16 x) + W1 convt.
__global__ __launch_bounds__(256) void prep1_k(
    const float* __restrict__ x, const float* __restrict__ Wr,
    const float* __restrict__ br,
    int* __restrict__ tok_exp, float* __restrict__ tok_gate,
    const float* __restrict__ W1, u16* __restrict__ W1t,
    u16* __restrict__ Xbf, int T) {
  __shared__ __align__(16) float Tf[128 * 64];   // 32KB
  const int bid = blockIdx.x;
  const int NBR = T / 4;
  if (bid >= NBR) {
    convt_gl<HD, DFF>(W1, W1t, bid - NBR, Tf);   // W1 -> panels [HD/64][DFF][64]
    return;
  }
  const int w = threadIdx.x >> 6, l = threadIdx.x & 63;
  const int t = bid * 4 + w;
  const float4* xr = (const float4*)(x + (size_t)t * HD);
  float acc[NEXP];
#pragma unroll
  for (int j = 0; j < NEXP; ++j) acc[j] = 0.f;
#pragma unroll
  for (int i = 0; i < 4; ++i) {
    float4 v = xr[l + i * 64];
    unsigned pa = cvtpk(v.x, v.y), pb = cvtpk(v.z, v.w);
    *(uint2*)&Xbf[(size_t)t * HD + (l + i * 64) * 4] = make_uint2(pa, pb);
    const int h = (l + i * 64) * 4;
    const float* w0 = Wr + (size_t)h * NEXP;
#pragma unroll
    for (int c = 0; c < 4; ++c) {
      float xv = (c == 0) ? v.x : (c == 1) ? v.y : (c == 2) ? v.z : v.w;
      const float4* wr4 = (const float4*)(w0 + c * NEXP);
      float4 a = wr4[0], b = wr4[1];
      acc[0] += xv * a.x; acc[1] += xv * a.y; acc[2] += xv * a.z; acc[3] += xv * a.w;
      acc[4] += xv * b.x; acc[5] += xv * b.y; acc[6] += xv * b.z; acc[7] += xv * b.w;
    }
  }
#pragma unroll
  for (int j = 0; j < NEXP; ++j)
#pragma unroll
    for (int off = 32; off > 0; off >>= 1) acc[j] += __shfl_xor(acc[j], off);
  if (l == 0) {
    float lg[NEXP];
    float best = acc[0] + br[0]; int bi = 0;
    lg[0] = best;
#pragma unroll
    for (int j = 1; j < NEXP; ++j) {
      lg[j] = acc[j] + br[j];
      if (lg[j] > best) { best = lg[j]; bi = j; }
    }
    float s = 0.f;
#pragma unroll
    for (int j = 0; j < NEXP; ++j) s += expf(lg[j] - best);
    tok_exp[t] = bi;
    tok_gate[t] = 1.0f / s;
  }
}

// merged scan+gather: single wave. Counts, prefix, tile table, then perm/gatep
// via LDS cursor atomics (wave-serial, deterministic).
__global__ __launch_bounds__(64) void scan_gather_k(const int* __restrict__ tok_exp,
    const float* __restrict__ tok_gate, int T,
    int* __restrict__ seg, int* __restrict__ ntile,
    int* __restrict__ tile_e, int* __restrict__ tile_m,
    int* __restrict__ perm, float* __restrict__ gatep) {
  __shared__ int lcur[NEXP];
  const int l = threadIdx.x;
  int cnt[NEXP];
#pragma unroll
  for (int j = 0; j < NEXP; ++j) cnt[j] = 0;
  for (int i = l; i < T; i += 64) {
    int e = tok_exp[i];
#pragma unroll
    for (int j = 0; j < NEXP; ++j) cnt[j] += (e == j) ? 1 : 0;
  }
#pragma unroll
  for (int j = 0; j < NEXP; ++j)
#pragma unroll
    for (int off = 32; off > 0; off >>= 1) cnt[j] += __shfl_xor(cnt[j], off);
  if (l == 0) {
    int s = 0, nt = 0;
#pragma unroll
    for (int e = 0; e < NEXP; ++e) {
      seg[e] = s; lcur[e] = s;
      int c = cnt[e];
      for (int m = 0; m < c; m += BM) { tile_e[nt] = e; tile_m[nt] = m; ++nt; }
      s += c;
    }
    seg[NEXP] = s;
    ntile[0] = nt;
  }
  __syncthreads();
  for (int t = l; t < T; t += 64) {
    int e = tok_exp[t];
    int pos = atomicAdd(&lcur[e], 1);
    perm[pos] = t;
    gatep[pos] = tok_gate[t];
  }
}

// Grouped GEMM body, BK=64, XOR-swizzled LDS, double-buffered single-barrier.
// A: AIND ? Xbf[perm[s0+row]] : A[s0+row]  ([T][KD] bf16 rows).
// B: Wp panels [KD/64][ND][64] bf16 (per-tt stride = ND*64).
// EPI 0: H1out = bf16(relu(acc+bias)).   EPI 2: Pt[ks][row][n] = acc (f32 partial).
template <int KD, int ND, int EPI, int KSPLIT, bool AIND>
__device__ __forceinline__ void gemm_body(
    u16* __restrict__ sh,   // 4 x TILE_U16: As0 | Bs0 | As1 | Bs1
    const u16* __restrict__ A, const u16* __restrict__ Bp,
    const float* __restrict__ bias, const int* __restrict__ seg,
    const int* __restrict__ ntile, const int* __restrict__ tile_e,
    const int* __restrict__ tile_m, const int* __restrict__ perm,
    u16* __restrict__ H1out, float* __restrict__ Pt,
    int bx, int by, int ks) {
  if (by >= ntile[0]) return;
  const int e  = tile_e[by];
  const int m0 = tile_m[by];
  const int s0 = seg[e];
  const int cnt = seg[e + 1] - s0;
  const int n0 = bx * BN;
  constexpr int NT = (KD / KSPLIT) / BK;
  constexpr size_t BSTEP = (size_t)ND * 64;      // one k-panel of B
  const int kbase = ks * (KD / KSPLIT);

  const int t = threadIdx.x;
  const int l = t & 63, w = t >> 6;
  const int wr = w >> 1, wc = w & 1;

  const f32x4 fzero = {0.f, 0.f, 0.f, 0.f};
  f32x4 acc[4][4];
#pragma unroll
  for (int i = 0; i < 4; ++i)
#pragma unroll
    for (int j = 0; j < 4; ++j) acc[i][j] = fzero;

  const int sub = t & 7, r8 = t >> 3;
  const int koff = (sub ^ (r8 & 7)) * 8;
  int aoff[4], boff[4];
  const u16* bte = Bp + (size_t)e * ND * KD;
#pragma unroll
  for (int c = 0; c < 4; ++c) {
    int row = c * 32 + r8;
    int rg = m0 + row; if (rg >= cnt) rg = cnt - 1;
    int arow;
    if constexpr (AIND) arow = perm[s0 + rg];   // token index
    else arow = s0 + rg;                         // positional
    aoff[c] = arow * KD + kbase + koff;
    boff[c] = (kbase / 64) * (int)BSTEP + (n0 + row) * 64 + koff;
  }

  u16* Ac = sh;
  u16* Bc = sh + TILE_U16;
  u16* An = sh + 2 * TILE_U16;
  u16* Bn = sh + 3 * TILE_U16;

#define STAGE(pa, pb, tt) do { \
    _Pragma("unroll") for (int c_ = 0; c_ < 4; ++c_) \
      gload_lds16(A + (size_t)aoff[c_] + (size_t)(tt) * BK, (pa) + (c_ * 256 + t) * 8); \
    _Pragma("unroll") for (int c_ = 0; c_ < 4; ++c_) \
      gload_lds16(bte + (size_t)boff[c_] + (size_t)(tt) * BSTEP, (pb) + (c_ * 256 + t) * 8); \
  } while (0)

#define COMPUTE(pa, pb) do { \
    _Pragma("unroll") for (int s_ = 0; s_ < 2; ++s_) { \
      const int fo_ = ((s_ * 4 + (l >> 4)) ^ (l & 7)) * 8; \
      s16x8 af_[4], bf_[4]; \
      _Pragma("unroll") for (int mi_ = 0; mi_ < 4; ++mi_) \
        af_[mi_] = *(const s16x8*)&(pa)[(wr * 64 + mi_ * 16 + (l & 15)) * BK + fo_]; \
      _Pragma("unroll") for (int ni_ = 0; ni_ < 4; ++ni_) \
        bf_[ni_] = *(const s16x8*)&(pb)[(wc * 64 + ni_ * 16 + (l & 15)) * BK + fo_]; \
      _Pragma("unroll") for (int mi_ = 0; mi_ < 4; ++mi_) \
        _Pragma("unroll") for (int ni_ = 0; ni_ < 4; ++ni_) \
          acc[mi_][ni_] = __builtin_amdgcn_mfma_f32_16x16x32_bf16(af_[mi_], bf_[ni_], acc[mi_][ni_], 0, 0, 0); \
    } \
  } while (0)

  STAGE(Ac, Bc, 0);
  __syncthreads();
  for (int tt = 0; tt < NT; ++tt) {
    if (tt + 1 < NT) STAGE(An, Bn, tt + 1);   // hides under COMPUTE below
    COMPUTE(Ac, Bc);
    if (tt + 1 < NT) {
      __syncthreads();                         // next stage landed; cur reads done
      u16* xp;
      xp = Ac; Ac = An; An = xp;
      xp = Bc; Bc = Bn; Bn = xp;
    }
  }

#undef STAGE
#undef COMPUTE

  const int lr = (l >> 4) * 4;
  const int lc = l & 15;

  if constexpr (EPI == 0) {
    float bv2[4];
#pragma unroll
    for (int ni = 0; ni < 4; ++ni)
      bv2[ni] = bias[(size_t)e * ND + n0 + wc * 64 + ni * 16 + lc];
#pragma unroll
    for (int mi = 0; mi < 4; ++mi) {
#pragma unroll
      for (int r = 0; r < 4; ++r) {
        int row = m0 + wr * 64 + mi * 16 + lr + r;
        if (row < cnt) {
          u16* hrow = H1out + (size_t)(s0 + row) * ND + n0 + wc * 64;
#pragma unroll
          for (int ni = 0; ni < 4; ++ni) {
            float v = acc[mi][ni][r] + bv2[ni];
            v = v > 0.f ? v : 0.f;
            hrow[ni * 16 + lc] = f2bf(v);
          }
        }
      }
    }
  } else {
    const int totT = seg[NEXP];
#pragma unroll
    for (int mi = 0; mi < 4; ++mi) {
#pragma unroll
      for (int r = 0; r < 4; ++r) {
        int row = m0 + wr * 64 + mi * 16 + lr + r;
        if (row < cnt) {
          float* prow = Pt + ((size_t)ks * totT + s0 + row) * ND + n0 + wc * 64;
#pragma unroll
          for (int ni = 0; ni < 4; ++ni)
            prow[ni * 16 + lc] = acc[mi][ni][r];
        }
      }
    }
  }
}

// Fused: GEMM1 blocks (XCD-chunked n-tiles) first, then W2-convt blocks.
// XCD c (bid%8 under round-robin dispatch) owns n-tiles {4c..4c+3} for ALL
// m-tiles -> its 4 B-panels (1MB) stay L2-resident instead of streaming 8MB
// through every XCD's L2 (GEMM1 is L3-BW-bound on B re-reads).
__global__ __launch_bounds__(256, 2) void gemm1_fused_k(
    const u16* __restrict__ Xbf, const u16* __restrict__ W1t,
    const float* __restrict__ b1, const int* __restrict__ seg,
    const int* __restrict__ ntile, const int* __restrict__ tile_e,
    const int* __restrict__ tile_m, const int* __restrict__ perm,
    u16* __restrict__ H1,
    const float* __restrict__ W2, u16* __restrict__ W2t, int ng1) {
  __shared__ __align__(16) u16 sh[4 * TILE_U16];   // 64KB; convt uses first 32KB
  const int bid = blockIdx.x;
  if (bid < ng1) {
    const int c = bid & 7, j = bid >> 3;           // 1248 = 8 * 4 * 39, bijective
    const int bx = (c << 2) | (j & 3);
    const int by = j >> 2;
    gemm_body<HD, DFF, 0, 1, true>(sh, Xbf, W1t, b1, seg, ntile, tile_e, tile_m,
                                   perm, H1, nullptr, bx, by, 0);
  } else {
    convt_gl<DFF, HD>(W2, W2t, bid - ng1, (float*)sh);   // W2 -> panels
  }
}

__global__ __launch_bounds__(256, 2) void gemm2_k(
    const u16* __restrict__ H1, const u16* __restrict__ W2t,
    const int* __restrict__ seg, const int* __restrict__ ntile,
    const int* __restrict__ tile_e, const int* __restrict__ tile_m,
    float* __restrict__ Pt) {
  __shared__ __align__(16) u16 sh[4 * TILE_U16];
  gemm_body<DFF, HD, 2, 2, false>(sh, H1, W2t, nullptr, seg, ntile, tile_e,
                                  tile_m, nullptr, nullptr, Pt,
                                  blockIdx.x, blockIdx.y, blockIdx.z);
}

// out[perm[pos]] = gate[pos] * (b2[e] + sum_ks Pt[ks][pos][:])   (KSPLIT=2)
__global__ __launch_bounds__(256) void reduce_k(const float* __restrict__ Pt,
    const float* __restrict__ b2, const int* __restrict__ perm,
    const float* __restrict__ gatep, const int* __restrict__ tok_exp,
    float* __restrict__ out) {
  const int pos = blockIdx.x;
  const int totT = gridDim.x;
  const int tok = perm[pos];
  const float g = gatep[pos];
  const int e = tok_exp[tok];
  const int h = threadIdx.x * 4;
  float4 s = *(const float4*)(Pt + ((size_t)0 * totT + pos) * HD + h);
  float4 p = *(const float4*)(Pt + ((size_t)1 * totT + pos) * HD + h);
  s.x += p.x; s.y += p.y; s.z += p.z; s.w += p.w;
  float4 b = *(const float4*)(b2 + (size_t)e * HD + h);
  float4 o;
  o.x = (s.x + b.x) * g; o.y = (s.y + b.y) * g;
  o.z = (s.z + b.z) * g; o.w = (s.w + b.w) * g;
  *(float4*)(out + (size_t)tok * HD + h) = o;
}

extern "C" void kernel_launch(void* const* d_in, const int* in_sizes, int n_in,
                              void* d_out, int out_size, void* d_ws, size_t ws_size,
                              hipStream_t stream) {
  const float* x  = (const float*)d_in[0];
  const float* Wr = (const float*)d_in[1];
  const float* br = (const float*)d_in[2];
  const float* W1 = (const float*)d_in[3];
  const float* b1 = (const float*)d_in[4];
  const float* W2 = (const float*)d_in[5];
  const float* b2 = (const float*)d_in[6];
  float* out = (float*)d_out;

  const int T = in_sizes[0] / HD;   // 4096 tokens
  char* ws = (char*)d_ws;
  int*   seg      = (int*)(ws + 128);
  int*   ntile    = (int*)(ws + 192);
  int*   tile_e   = (int*)(ws + 256);
  int*   tile_m   = (int*)(ws + 512);
  int*   tok_exp  = (int*)(ws + 1024);
  float* tok_gate = (float*)(ws + 1024 + 4 * (size_t)T);
  int*   perm     = (int*)(ws + 1024 + 8 * (size_t)T);
  float* gatep    = (float*)(ws + 1024 + 12 * (size_t)T);
  u16*   Xbf      = (u16*)(ws + 1024 + 16 * (size_t)T);                       // T*HD bf16 (8MB), token order
  u16*   H1       = (u16*)(ws + 1024 + 16 * (size_t)T + 2 * (size_t)T * HD);  // T*DFF bf16 (32MB)
  size_t off2     = 1024 + 16 * (size_t)T + 2 * (size_t)T * HD + 2 * (size_t)T * DFF;
  u16*   W1t      = (u16*)(ws + off2);                                        // panel layout (64MB)
  u16*   W2t      = (u16*)(ws + off2 + 2 * (size_t)NEXP * HD * DFF);          // panel layout (64MB)
  float* Pt       = (float*)W1t;   // GEMM2 split-K partials (2*T*HD f32 = 32MB) reuse W1t

  const int NBR = T / 4;
  const int NCT = 512 * NEXP;   // 4096 convt tiles per weight
  hipLaunchKernelGGL(prep1_k, dim3(NBR + NCT), dim3(256), 0, stream,
                     x, Wr, br, tok_exp, tok_gate, W1, W1t, Xbf, T);
  hipLaunchKernelGGL(scan_gather_k, dim3(1), dim3(64), 0, stream,
                     tok_exp, tok_gate, T, seg, ntile, tile_e, tile_m, perm, gatep);
  const int maxtile = (T + BM - 1) / BM + NEXP - 1;   // 39 worst case
  const int ng1 = (DFF / BN) * maxtile;               // 1248 GEMM1 blocks
  hipLaunchKernelGGL(gemm1_fused_k, dim3(ng1 + NCT), dim3(256), 0, stream,
                     Xbf, W1t, b1, seg, ntile, tile_e, tile_m, perm, H1, W2, W2t, ng1);
  hipLaunchKernelGGL(gemm2_k, dim3(HD / BN, maxtile, 2), dim3(256), 0, stream,
                     H1, W2t, seg, ntile, tile_e, tile_m, Pt);
  hipLaunchKernelGGL(reduce_k, dim3(T), dim3(256), 0, stream, Pt, b2, perm, gatep, tok_exp, out);
}

// Round 22
// 251.618 us; speedup vs baseline: 1.0288x; 1.0257x over previous
//
#include <hip/hip_runtime.h>
#include <stdint.h>

typedef unsigned short u16;
typedef __attribute__((ext_vector_type(8))) short s16x8;   // 8 bf16 in 4 VGPRs
typedef __attribute__((ext_vector_type(4))) float f32x4;   // MFMA accumulator
typedef __attribute__((ext_vector_type(4))) unsigned uint4v;

#define NEXP 8
#define HD 1024
#define DFF 4096
#define BM 128
#define BN 128
#define BK 64     // 128B rows; XOR-swizzled LDS (T21 both-sides)

#define TILE_U16 (BM * BK)   // 8192 u16 = 16KB per GEMM LDS tile

__device__ __forceinline__ u16 f2bf(float f) {
  union { float f; unsigned u; } c; c.f = f;
  unsigned r = c.u + 0x7fffu + ((c.u >> 16) & 1u);   // RNE
  return (u16)(r >> 16);
}

__device__ __forceinline__ unsigned cvtpk(float a, float b) {
  unsigned r;
  asm("v_cvt_pk_bf16_f32 %0, %1, %2" : "=v"(r) : "v"(a), "v"(b));
  return r;   // lo = bf16(a), hi = bf16(b)
}

__device__ __forceinline__ void gload_lds16(const void* g, const void* l) {
  __builtin_amdgcn_global_load_lds(
      (const __attribute__((address_space(1))) unsigned int*)(uintptr_t)g,
      (__attribute__((address_space(3))) unsigned int*)(unsigned)(uintptr_t)l,
      16, 0, 0);
}

// Transpose+convert into k-panel-blocked layout:
// W f32 [K][N]  ->  Wp bf16 [K/64][N][64]  (panel kp, row n, 64 k-elems = 128B).
// Tile = 128k x 64n. Stage via gload_lds into Tf[128][64] (linear, coalesced).
// Phase 2: thread (p=t>>7, n=(t&127)>>1, kh=t&1) reads 32 Tf elems (2 lanes/bank,
// free), cvt_pk, stores 64B; lanes are address-consecutive -> 4KB contiguous
// per wave store instruction.
template <int K, int N>
__device__ __forceinline__ void convt_gl(const float* __restrict__ W,
    u16* __restrict__ Wp, int idx, float* __restrict__ Tf) {
  const int e = idx >> 9;                        // (K/128)*(N/64) = 512 tiles/expert
  const int ti = idx & 511;
  const int k0 = (ti % (K / 128)) * 128;
  const int n0 = (ti / (K / 128)) * 64;
  const int t = threadIdx.x;
  const float* src = W + (size_t)e * K * N + (size_t)k0 * N + n0;
#pragma unroll
  for (int c = 0; c < 8; ++c) {
    int slot = c * 256 + t;
    gload_lds16(src + (size_t)(slot >> 4) * N + (slot & 15) * 4, Tf + slot * 4);
  }
  __syncthreads();
  const int p = t >> 7, nl = (t & 127) >> 1, kh = t & 1;
  float v[32];
#pragma unroll
  for (int j = 0; j < 32; ++j)
    v[j] = Tf[(p * 64 + kh * 32 + j) * 64 + nl];
  uint4v q0, q1, q2, q3;
#pragma unroll
  for (int a = 0; a < 4; ++a) {
    q0[a] = cvtpk(v[2 * a], v[2 * a + 1]);
    q1[a] = cvtpk(v[8 + 2 * a], v[9 + 2 * a]);
    q2[a] = cvtpk(v[16 + 2 * a], v[17 + 2 * a]);
    q3[a] = cvtpk(v[24 + 2 * a], v[25 + 2 * a]);
  }
  u16* d = Wp + (size_t)e * K * N + ((size_t)(k0 / 64 + p)) * N * 64
         + (size_t)(n0 + nl) * 64 + kh * 32;
  *(uint4v*)d = q0;
  *(uint4v*)(d + 8) = q1;
  *(uint4v*)(d + 16) = q2;
  *(uint4v*)(d + 24) = q3;
}

// prep1: router (4 tokens/block, wave per token; emits bf16 x) + W1 convt.
__global__ __launch_bounds__(256) void prep1_k(
    const float* __restrict__ x, const float* __restrict__ Wr,
    const float* __restrict__ br,
    int* __restrict__ tok_exp, float* __restrict__ tok_gate,
    const float* __restrict__ W1, u16* __restrict__ W1t,
    u16* __restrict__ Xbf, int T) {
  __shared__ __align__(16) float Tf[128 * 64];   // 32KB
  const int bid = blockIdx.x;
  const int NBR = T / 4;
  if (bid >= NBR) {
    convt_gl<HD, DFF>(W1, W1t, bid - NBR, Tf);   // W1 -> panels [HD/64][DFF][64]
    return;
  }
  const int w = threadIdx.x >> 6, l = threadIdx.x & 63;
  const int t = bid * 4 + w;
  const float4* xr = (const float4*)(x + (size_t)t * HD);
  float acc[NEXP];
#pragma unroll
  for (int j = 0; j < NEXP; ++j) acc[j] = 0.f;
#pragma unroll
  for (int i = 0; i < 4; ++i) {
    float4 v = xr[l + i * 64];
    unsigned pa = cvtpk(v.x, v.y), pb = cvtpk(v.z, v.w);
    *(uint2*)&Xbf[(size_t)t * HD + (l + i * 64) * 4] = make_uint2(pa, pb);
    const int h = (l + i * 64) * 4;
    const float* w0 = Wr + (size_t)h * NEXP;
#pragma unroll
    for (int c = 0; c < 4; ++c) {
      float xv = (c == 0) ? v.x : (c == 1) ? v.y : (c == 2) ? v.z : v.w;
      const float4* wr4 = (const float4*)(w0 + c * NEXP);
      float4 a = wr4[0], b = wr4[1];
      acc[0] += xv * a.x; acc[1] += xv * a.y; acc[2] += xv * a.z; acc[3] += xv * a.w;
      acc[4] += xv * b.x; acc[5] += xv * b.y; acc[6] += xv * b.z; acc[7] += xv * b.w;
    }
  }
#pragma unroll
  for (int j = 0; j < NEXP; ++j)
#pragma unroll
    for (int off = 32; off > 0; off >>= 1) acc[j] += __shfl_xor(acc[j], off);
  if (l == 0) {
    float lg[NEXP];
    float best = acc[0] + br[0]; int bi = 0;
    lg[0] = best;
#pragma unroll
    for (int j = 1; j < NEXP; ++j) {
      lg[j] = acc[j] + br[j];
      if (lg[j] > best) { best = lg[j]; bi = j; }
    }
    float s = 0.f;
#pragma unroll
    for (int j = 0; j < NEXP; ++j) s += expf(lg[j] - best);
    tok_exp[t] = bi;
    tok_gate[t] = 1.0f / s;
  }
}

// scan: count experts from tok_exp (no atomics), prefix, tile table.
__global__ __launch_bounds__(64) void scan_k(const int* __restrict__ tok_exp, int T,
    int* __restrict__ seg, int* __restrict__ cursor,
    int* __restrict__ ntile, int* __restrict__ tile_e, int* __restrict__ tile_m) {
  const int l = threadIdx.x;
  int cnt[NEXP];
#pragma unroll
  for (int j = 0; j < NEXP; ++j) cnt[j] = 0;
  for (int i = l; i < T; i += 64) {
    int e = tok_exp[i];
#pragma unroll
    for (int j = 0; j < NEXP; ++j) cnt[j] += (e == j) ? 1 : 0;
  }
#pragma unroll
  for (int j = 0; j < NEXP; ++j)
#pragma unroll
    for (int off = 32; off > 0; off >>= 1) cnt[j] += __shfl_xor(cnt[j], off);
  if (l == 0) {
    int s = 0, nt = 0;
#pragma unroll
    for (int e = 0; e < NEXP; ++e) {
      seg[e] = s; cursor[e] = s;
      int c = cnt[e];
      for (int m = 0; m < c; m += BM) { tile_e[nt] = e; tile_m[nt] = m; ++nt; }
      s += c;
    }
    seg[NEXP] = s;
    ntile[0] = nt;
  }
}

// gather-lite: build perm/gatep only (no data copy) — 1 thread/token.
__global__ __launch_bounds__(256) void gatherlite_k(const int* __restrict__ tok_exp,
    const float* __restrict__ tok_gate, int* __restrict__ cursor,
    int* __restrict__ perm, float* __restrict__ gatep) {
  const int t = blockIdx.x * 256 + threadIdx.x;
  int e = tok_exp[t];
  int pos = atomicAdd(&cursor[e], 1);
  perm[pos] = t;
  gatep[pos] = tok_gate[t];
}

// Grouped GEMM body, BK=64, XOR-swizzled LDS, double-buffered single-barrier.
// A: AIND ? Xbf[perm[s0+row]] : A[s0+row]  ([T][KD] bf16 rows).
// B: Wp panels [KD/64][ND][64] bf16 (per-tt stride = ND*64).
// EPI 0: H1out = bf16(relu(acc+bias)).   EPI 2: Pt[ks][row][n] = acc (f32 partial).
template <int KD, int ND, int EPI, int KSPLIT, bool AIND>
__device__ __forceinline__ void gemm_body(
    u16* __restrict__ sh,   // 4 x TILE_U16: As0 | Bs0 | As1 | Bs1
    const u16* __restrict__ A, const u16* __restrict__ Bp,
    const float* __restrict__ bias, const int* __restrict__ seg,
    const int* __restrict__ ntile, const int* __restrict__ tile_e,
    const int* __restrict__ tile_m, const int* __restrict__ perm,
    u16* __restrict__ H1out, float* __restrict__ Pt,
    int bx, int by, int ks) {
  if (by >= ntile[0]) return;
  const int e  = tile_e[by];
  const int m0 = tile_m[by];
  const int s0 = seg[e];
  const int cnt = seg[e + 1] - s0;
  const int n0 = bx * BN;
  constexpr int NT = (KD / KSPLIT) / BK;
  constexpr size_t BSTEP = (size_t)ND * 64;      // one k-panel of B
  const int kbase = ks * (KD / KSPLIT);

  const int t = threadIdx.x;
  const int l = t & 63, w = t >> 6;
  const int wr = w >> 1, wc = w & 1;

  const f32x4 fzero = {0.f, 0.f, 0.f, 0.f};
  f32x4 acc[4][4];
#pragma unroll
  for (int i = 0; i < 4; ++i)
#pragma unroll
    for (int j = 0; j < 4; ++j) acc[i][j] = fzero;

  const int sub = t & 7, r8 = t >> 3;
  const int koff = (sub ^ (r8 & 7)) * 8;
  int aoff[4], boff[4];
  const u16* bte = Bp + (size_t)e * ND * KD;
#pragma unroll
  for (int c = 0; c < 4; ++c) {
    int row = c * 32 + r8;
    int rg = m0 + row; if (rg >= cnt) rg = cnt - 1;
    int arow;
    if constexpr (AIND) arow = perm[s0 + rg];   // token index
    else arow = s0 + rg;                         // positional
    aoff[c] = arow * KD + kbase + koff;
    boff[c] = (kbase / 64) * (int)BSTEP + (n0 + row) * 64 + koff;
  }

  u16* Ac = sh;
  u16* Bc = sh + TILE_U16;
  u16* An = sh + 2 * TILE_U16;
  u16* Bn = sh + 3 * TILE_U16;

#define STAGE(pa, pb, tt) do { \
    _Pragma("unroll") for (int c_ = 0; c_ < 4; ++c_) \
      gload_lds16(A + (size_t)aoff[c_] + (size_t)(tt) * BK, (pa) + (c_ * 256 + t) * 8); \
    _Pragma("unroll") for (int c_ = 0; c_ < 4; ++c_) \
      gload_lds16(bte + (size_t)boff[c_] + (size_t)(tt) * BSTEP, (pb) + (c_ * 256 + t) * 8); \
  } while (0)

#define COMPUTE(pa, pb) do { \
    _Pragma("unroll") for (int s_ = 0; s_ < 2; ++s_) { \
      const int fo_ = ((s_ * 4 + (l >> 4)) ^ (l & 7)) * 8; \
      s16x8 af_[4], bf_[4]; \
      _Pragma("unroll") for (int mi_ = 0; mi_ < 4; ++mi_) \
        af_[mi_] = *(const s16x8*)&(pa)[(wr * 64 + mi_ * 16 + (l & 15)) * BK + fo_]; \
      _Pragma("unroll") for (int ni_ = 0; ni_ < 4; ++ni_) \
        bf_[ni_] = *(const s16x8*)&(pb)[(wc * 64 + ni_ * 16 + (l & 15)) * BK + fo_]; \
      _Pragma("unroll") for (int mi_ = 0; mi_ < 4; ++mi_) \
        _Pragma("unroll") for (int ni_ = 0; ni_ < 4; ++ni_) \
          acc[mi_][ni_] = __builtin_amdgcn_mfma_f32_16x16x32_bf16(af_[mi_], bf_[ni_], acc[mi_][ni_], 0, 0, 0); \
    } \
  } while (0)

  STAGE(Ac, Bc, 0);
  __syncthreads();
  for (int tt = 0; tt < NT; ++tt) {
    if (tt + 1 < NT) STAGE(An, Bn, tt + 1);   // hides under COMPUTE below
    COMPUTE(Ac, Bc);
    if (tt + 1 < NT) {
      __syncthreads();                         // next stage landed; cur reads done
      u16* xp;
      xp = Ac; Ac = An; An = xp;
      xp = Bc; Bc = Bn; Bn = xp;
    }
  }

#undef STAGE
#undef COMPUTE

  const int lr = (l >> 4) * 4;
  const int lc = l & 15;

  if constexpr (EPI == 0) {
    float bv2[4];
#pragma unroll
    for (int ni = 0; ni < 4; ++ni)
      bv2[ni] = bias[(size_t)e * ND + n0 + wc * 64 + ni * 16 + lc];
#pragma unroll
    for (int mi = 0; mi < 4; ++mi) {
#pragma unroll
      for (int r = 0; r < 4; ++r) {
        int row = m0 + wr * 64 + mi * 16 + lr + r;
        if (row < cnt) {
          u16* hrow = H1out + (size_t)(s0 + row) * ND + n0 + wc * 64;
#pragma unroll
          for (int ni = 0; ni < 4; ++ni) {
            float v = acc[mi][ni][r] + bv2[ni];
            v = v > 0.f ? v : 0.f;
            hrow[ni * 16 + lc] = f2bf(v);
          }
        }
      }
    }
  } else {
    const int totT = seg[NEXP];
#pragma unroll
    for (int mi = 0; mi < 4; ++mi) {
#pragma unroll
      for (int r = 0; r < 4; ++r) {
        int row = m0 + wr * 64 + mi * 16 + lr + r;
        if (row < cnt) {
          float* prow = Pt + ((size_t)ks * totT + s0 + row) * ND + n0 + wc * 64;
#pragma unroll
          for (int ni = 0; ni < 4; ++ni)
            prow[ni * 16 + lc] = acc[mi][ni][r];
        }
      }
    }
  }
}

// Fused: GEMM1 blocks first, then W2-convt blocks.
// W2t is only read by the NEXT launch (gemm2) -> completion guaranteed.
__global__ __launch_bounds__(256, 2) void gemm1_fused_k(
    const u16* __restrict__ Xbf, const u16* __restrict__ W1t,
    const float* __restrict__ b1, const int* __restrict__ seg,
    const int* __restrict__ ntile, const int* __restrict__ tile_e,
    const int* __restrict__ tile_m, const int* __restrict__ perm,
    u16* __restrict__ H1,
    const float* __restrict__ W2, u16* __restrict__ W2t, int ng1) {
  __shared__ __align__(16) u16 sh[4 * TILE_U16];   // 64KB; convt uses first 32KB
  const int bid = blockIdx.x;
  if (bid < ng1) {
    gemm_body<HD, DFF, 0, 1, true>(sh, Xbf, W1t, b1, seg, ntile, tile_e, tile_m,
                                   perm, H1, nullptr,
                                   bid % (DFF / BN), bid / (DFF / BN), 0);
  } else {
    convt_gl<DFF, HD>(W2, W2t, bid - ng1, (float*)sh);   // W2 -> panels [DFF/64][HD][64]
  }
}

__global__ __launch_bounds__(256, 2) void gemm2_k(
    const u16* __restrict__ H1, const u16* __restrict__ W2t,
    const int* __restrict__ seg, const int* __restrict__ ntile,
    const int* __restrict__ tile_e, const int* __restrict__ tile_m,
    float* __restrict__ Pt) {
  __shared__ __align__(16) u16 sh[4 * TILE_U16];
  gemm_body<DFF, HD, 2, 2, false>(sh, H1, W2t, nullptr, seg, ntile, tile_e,
                                  tile_m, nullptr, nullptr, Pt,
                                  blockIdx.x, blockIdx.y, blockIdx.z);
}

// out[perm[pos]] = gate[pos] * (b2[e] + sum_ks Pt[ks][pos][:])   (KSPLIT=2)
__global__ __launch_bounds__(256) void reduce_k(const float* __restrict__ Pt,
    const float* __restrict__ b2, const int* __restrict__ perm,
    const float* __restrict__ gatep, const int* __restrict__ tok_exp,
    float* __restrict__ out) {
  const int pos = blockIdx.x;
  const int totT = gridDim.x;
  const int tok = perm[pos];
  const float g = gatep[pos];
  const int e = tok_exp[tok];
  const int h = threadIdx.x * 4;
  float4 s = *(const float4*)(Pt + ((size_t)0 * totT + pos) * HD + h);
  float4 p = *(const float4*)(Pt + ((size_t)1 * totT + pos) * HD + h);
  s.x += p.x; s.y += p.y; s.z += p.z; s.w += p.w;
  float4 b = *(const float4*)(b2 + (size_t)e * HD + h);
  float4 o;
  o.x = (s.x + b.x) * g; o.y = (s.y + b.y) * g;
  o.z = (s.z + b.z) * g; o.w = (s.w + b.w) * g;
  *(float4*)(out + (size_t)tok * HD + h) = o;
}

extern "C" void kernel_launch(void* const* d_in, const int* in_sizes, int n_in,
                              void* d_out, int out_size, void* d_ws, size_t ws_size,
                              hipStream_t stream) {
  const float* x  = (const float*)d_in[0];
  const float* Wr = (const float*)d_in[1];
  const float* br = (const float*)d_in[2];
  const float* W1 = (const float*)d_in[3];
  const float* b1 = (const float*)d_in[4];
  const float* W2 = (const float*)d_in[5];
  const float* b2 = (const float*)d_in[6];
  float* out = (float*)d_out;

  const int T = in_sizes[0] / HD;   // 4096 tokens
  char* ws = (char*)d_ws;
  int*   cursor   = (int*)(ws + 64);
  int*   seg      = (int*)(ws + 128);
  int*   ntile    = (int*)(ws + 192);
  int*   tile_e   = (int*)(ws + 256);
  int*   tile_m   = (int*)(ws + 512);
  int*   tok_exp  = (int*)(ws + 1024);
  float* tok_gate = (float*)(ws + 1024 + 4 * (size_t)T);
  int*   perm     = (int*)(ws + 1024 + 8 * (size_t)T);
  float* gatep    = (float*)(ws + 1024 + 12 * (size_t)T);
  u16*   Xbf      = (u16*)(ws + 1024 + 16 * (size_t)T);                       // T*HD bf16 (8MB), token order
  u16*   H1       = (u16*)(ws + 1024 + 16 * (size_t)T + 2 * (size_t)T * HD);  // T*DFF bf16 (32MB)
  size_t off2     = 1024 + 16 * (size_t)T + 2 * (size_t)T * HD + 2 * (size_t)T * DFF;
  u16*   W1t      = (u16*)(ws + off2);                                        // panel layout (64MB)
  u16*   W2t      = (u16*)(ws + off2 + 2 * (size_t)NEXP * HD * DFF);          // panel layout (64MB)
  float* Pt       = (float*)W1t;   // GEMM2 split-K partials (2*T*HD f32 = 32MB) reuse W1t

  const int NBR = T / 4;
  const int NCT = 512 * NEXP;   // 4096 convt tiles per weight
  hipLaunchKernelGGL(prep1_k, dim3(NBR + NCT), dim3(256), 0, stream,
                     x, Wr, br, tok_exp, tok_gate, W1, W1t, Xbf, T);
  hipLaunchKernelGGL(scan_k, dim3(1), dim3(64), 0, stream,
                     tok_exp, T, seg, cursor, ntile, tile_e, tile_m);
  hipLaunchKernelGGL(gatherlite_k, dim3(T / 256), dim3(256), 0, stream,
                     tok_exp, tok_gate, cursor, perm, gatep);
  const int maxtile = (T + BM - 1) / BM + NEXP - 1;   // 39 worst case
  const int ng1 = (DFF / BN) * maxtile;               // 1248 GEMM1 blocks
  hipLaunchKernelGGL(gemm1_fused_k, dim3(ng1 + NCT), dim3(256), 0, stream,
                     Xbf, W1t, b1, seg, ntile, tile_e, tile_m, perm, H1, W2, W2t, ng1);
  hipLaunchKernelGGL(gemm2_k, dim3(HD / BN, maxtile, 2), dim3(256), 0, stream,
                     H1, W2t, seg, ntile, tile_e, tile_m, Pt);
  hipLaunchKernelGGL(reduce_k, dim3(T), dim3(256), 0, stream, Pt, b2, perm, gatep, tok_exp, out);
}